// Round 4
// baseline (318.768 us; speedup 1.0000x reference)
//
#include <hip/hip_runtime.h>

// WARP loss: B=4096 rows, Y=10000 labels, T=128 trials.
// input [B,Y] f32, target [B,Y] f32 (exactly one-hot), neg_candidates [B,T] i32.
// out[0] = sum_rows log((Y-1)/num_trials) * (1 - s_pos + s_neg),
// num_trials = 1 + first t with 1 + s_neg_t - s_pos >= 0 (row skipped if none).
//
// Structure: one 256-thread block per row.
//   - 128 candidate gathers prefetched before the scan (latency overlapped).
//   - one-hot scan of target with early exit, polled per 8 KB chunk
//     (expected ~60% of the 40 KB row read; uniform positive position).
//   - the hit thread immediately gathers s_pos -> LDS (overlaps barrier).
//   - winner thread (first accepted trial) computes loss + atomicAdd.

constexpr int Yc    = 10000;
constexpr int Tc    = 128;
constexpr int BLOCK = 256;
constexpr int NV4   = Yc / 4;   // 2500 float4 per row

typedef float f32x4 __attribute__((ext_vector_type(4)));

__global__ __launch_bounds__(BLOCK) void warp_loss_kernel(
        const float* __restrict__ input,
        const float* __restrict__ target,
        const int*   __restrict__ neg,
        float* __restrict__ out) {
    const int    row     = blockIdx.x;
    const int    tid     = threadIdx.x;
    const size_t rowbase = (size_t)row * Yc;

    __shared__ int   sh_found;   // early-exit flag
    __shared__ int   sh_first;   // first accepted trial (Tc if none)
    __shared__ float sh_spos;    // positive score (written by the hit thread)

    // Prefetch candidate scores: independent of the scan, latency overlaps it.
    float s_cand = 0.0f;
    if (tid < Tc) {
        int c  = neg[row * Tc + tid];
        s_cand = input[rowbase + c];
    }

    if (tid == 0) { sh_found = 0; sh_first = Tc; }
    __syncthreads();

    // ---- one-hot scan with early exit (poll shared flag every 8 KB chunk) ----
    const f32x4* trow = reinterpret_cast<const f32x4*>(target + rowbase);
    for (int base = 0; base < NV4; base += 2 * BLOCK) {
        if (__hip_atomic_load(&sh_found, __ATOMIC_RELAXED,
                              __HIP_MEMORY_SCOPE_WORKGROUP)) break;
        int  i0 = base + tid;
        int  i1 = i0 + BLOCK;
        bool b0 = i0 < NV4, b1 = i1 < NV4;
        f32x4 v0 = {}, v1 = {};
        if (b0) v0 = __builtin_nontemporal_load(trow + i0);  // streamed once
        if (b1) v1 = __builtin_nontemporal_load(trow + i1);
        int hit = -1;
        if (b0) {
            if (v0[0] > 0.5f) hit = 4 * i0 + 0;
            if (v0[1] > 0.5f) hit = 4 * i0 + 1;
            if (v0[2] > 0.5f) hit = 4 * i0 + 2;
            if (v0[3] > 0.5f) hit = 4 * i0 + 3;
        }
        if (b1) {
            if (v1[0] > 0.5f) hit = 4 * i1 + 0;
            if (v1[1] > 0.5f) hit = 4 * i1 + 1;
            if (v1[2] > 0.5f) hit = 4 * i1 + 2;
            if (v1[3] > 0.5f) hit = 4 * i1 + 3;
        }
        if (hit >= 0) {
            // Fused s_pos gather: overlaps other waves' scan + barrier wait.
            sh_spos = input[rowbase + hit];
            __hip_atomic_store(&sh_found, 1, __ATOMIC_RELAXED,
                               __HIP_MEMORY_SCOPE_WORKGROUP);
        }
    }
    __syncthreads();                       // publishes sh_spos to all threads
    const float s_pos = sh_spos;

    // ---- rejection sampling: first t with 1 + s_cand - s_pos >= 0 ----
    if (tid < Tc && (1.0f + s_cand - s_pos >= 0.0f)) atomicMin(&sh_first, tid);
    __syncthreads();

    // Winner computes the loss from its own registers; one atomic per row.
    if (tid == sh_first && tid < Tc) {
        int   nt = tid + 1;
        float L  = logf((float)((Yc - 1) / nt));   // integer floor-div, then log
        atomicAdd(out, L * (1.0f - s_pos + s_cand));
    }
}

extern "C" void kernel_launch(void* const* d_in, const int* in_sizes, int n_in,
                              void* d_out, int out_size, void* d_ws, size_t ws_size,
                              hipStream_t stream) {
    const float* input  = (const float*)d_in[0];
    const float* target = (const float*)d_in[1];
    const int*   neg    = (const int*)d_in[2];
    float* out = (float*)d_out;

    const int B = in_sizes[2] / Tc;  // 4096

    // Harness re-poisons d_out to 0xAA before every timed replay: zero it here.
    hipMemsetAsync(out, 0, sizeof(float), stream);
    warp_loss_kernel<<<B, BLOCK, 0, stream>>>(input, target, neg, out);
}